// Round 8
// baseline (343.539 us; speedup 1.0000x reference)
//
#include <hip/hip_runtime.h>
#include <hip/hip_bf16.h>

#define D 128
#define MARGIN 0.5f
#define NSPLIT 20      // 64 x 20 = 1280 blocks = exactly 5/CU (LDS-exact fit)

typedef __attribute__((ext_vector_type(8))) short bf16x8;
typedef __attribute__((ext_vector_type(4))) float f32x4;

// ---------------- prep: bf16 convert + sq + init ----------------
__global__ void prep_kernel(const float* __restrict__ x,
                            float* __restrict__ sq,
                            unsigned* __restrict__ ap,
                            unsigned* __restrict__ an,
                            __hip_bfloat16* __restrict__ xb,
                            unsigned* __restrict__ done, int n) {
    int tid = threadIdx.x;
    int row = blockIdx.x * 4 + (tid >> 6);
    int lane = tid & 63;
    const float2* xr = (const float2*)(x + (size_t)row * D);
    float2 v = xr[lane];
    __hip_bfloat162 b2;
    b2.x = __float2bfloat16(v.x);
    b2.y = __float2bfloat16(v.y);
    ((__hip_bfloat162*)(xb + (size_t)row * D))[lane] = b2;
    float s = v.x * v.x + v.y * v.y;
    #pragma unroll
    for (int o = 32; o > 0; o >>= 1) s += __shfl_xor(s, o, 64);
    if (lane == 0) {
        sq[row] = s;
        ap[row] = 0u;            // dist >= 0 -> 0 is a valid -inf for max
        an[row] = 0x7F800000u;   // +inf bits
    }
    if (blockIdx.x == 0 && tid == 0) *done = 0u;
}

// ---------------- gram: async B staging + fused final (last-block) -------
// Block = 4 waves = 128 i-rows (wave: 32 rows). j-tiles of 64 cols, K=128.
// B tile 16KB double-buffered = 32KB exactly -> 5 blocks/CU fills 160KB LDS.
// __launch_bounds__(256,5): VGPR cap 102 (5x102=510<=512/SIMD, perfect fit).
// Staging via global_load_lds w=16 (no VGPR round trip -> no spill). XOR
// swizzle on global src addr; ds_read frags 2-way (free). Last finishing
// block performs the loss reduction (saves a 6us launch).
__launch_bounds__(256, 5)
__global__ void gram_kernel(const __hip_bfloat16* __restrict__ xb,
                            const float* __restrict__ sq,
                            const int* __restrict__ tgt,
                            unsigned* __restrict__ ap,
                            unsigned* __restrict__ an,
                            unsigned* __restrict__ done,
                            float* __restrict__ out, int n) {
    __shared__ __align__(16) __hip_bfloat16 Bs[2][64 * D];

    const int tid  = threadIdx.x;
    const int wid  = tid >> 6;
    const int lane = tid & 63;
    const int quad = lane >> 4;
    const int l    = lane & 15;
    const int i0   = blockIdx.x * 128;
    const int NT   = n / 64;                          // 128 j-tiles
    const int jt_begin = (blockIdx.y * NT) / NSPLIT;  // uneven 6/7-tile splits
    const int jt_end   = ((blockIdx.y + 1) * NT) / NSPLIT;
    const int rowbase = i0 + wid * 32;

    // A fragments, register-resident: lane holds A[m=l][k=quad*8+j]
    bf16x8 afrag[2][4];
    {
        const __hip_bfloat16* abase = xb + (size_t)(rowbase + l) * D + quad * 8;
        #pragma unroll
        for (int mt = 0; mt < 2; ++mt)
            #pragma unroll
            for (int ks = 0; ks < 4; ++ks)
                afrag[mt][ks] = *(const bf16x8*)(abase + (size_t)mt * 16 * D + ks * 32);
    }

    int li[2][4];
    #pragma unroll
    for (int mt = 0; mt < 2; ++mt)
        #pragma unroll
        for (int reg = 0; reg < 4; ++reg)
            li[mt][reg] = tgt[rowbase + mt * 16 + quad * 4 + reg];

    float lap[8], lan[8];
    #pragma unroll
    for (int k = 0; k < 8; ++k) { lap[k] = -1e30f; lan[k] = 1e30f; }

    const int q0 = wid * 256;
    const char* xbb = (const char*)xb;

    #define PREFETCH(jt0, buf)                                                \
        do {                                                                  \
            _Pragma("unroll")                                                 \
            for (int i_ = 0; i_ < 4; ++i_) {                                  \
                int q_ = q0 + i_ * 64 + lane;                                 \
                int r_ = q_ >> 4;                                             \
                int c_ = (q_ & 15) ^ (r_ & 15);                               \
                const char* g_ = xbb + (size_t)((jt0) + r_) * 256             \
                                     + (size_t)c_ * 16;                       \
                char* l_ = (char*)&Bs[buf][0] + (size_t)(q0 + i_ * 64) * 16;  \
                __builtin_amdgcn_global_load_lds(                             \
                    (const __attribute__((address_space(1))) void*)g_,        \
                    (__attribute__((address_space(3))) void*)l_, 16, 0, 0);   \
            }                                                                 \
        } while (0)

    PREFETCH(jt_begin * 64, 0);
    __syncthreads();

    for (int jj = jt_begin; jj < jt_end; ++jj) {
        const int cur = (jj - jt_begin) & 1;
        if (jj + 1 < jt_end) PREFETCH((jj + 1) * 64, cur ^ 1);   // async

        const char* Bb = (const char*)&Bs[cur][0];
        const int jbase = jj * 64;
        #pragma unroll
        for (int jt = 0; jt < 4; ++jt) {
            f32x4 acc0 = (f32x4){0.f, 0.f, 0.f, 0.f};
            f32x4 acc1 = (f32x4){0.f, 0.f, 0.f, 0.f};
            #pragma unroll
            for (int ks = 0; ks < 4; ++ks) {
                int q = (jt * 16 + l) * 16 + ((ks * 4 + quad) ^ l);
                bf16x8 bfr = *(const bf16x8*)(Bb + (size_t)q * 16);
                acc0 = __builtin_amdgcn_mfma_f32_16x16x32_bf16(afrag[0][ks], bfr, acc0, 0, 0, 0);
                acc1 = __builtin_amdgcn_mfma_f32_16x16x32_bf16(afrag[1][ks], bfr, acc1, 0, 0, 0);
            }
            float sjc = sq[jbase + jt * 16 + l];
            int   tjc = tgt[jbase + jt * 16 + l];
            #pragma unroll
            for (int reg = 0; reg < 4; ++reg) {
                float t0 = fmaf(-2.0f, acc0[reg], sjc);
                float t1 = fmaf(-2.0f, acc1[reg], sjc);
                bool s0 = (li[0][reg] == tjc);
                bool s1 = (li[1][reg] == tjc);
                lap[reg]     = fmaxf(lap[reg],     s0 ? t0 : -1e30f);
                lan[reg]     = fminf(lan[reg],     s0 ? 1e30f : t0);
                lap[4 + reg] = fmaxf(lap[4 + reg], s1 ? t1 : -1e30f);
                lan[4 + reg] = fminf(lan[4 + reg], s1 ? 1e30f : t1);
            }
        }
        __syncthreads();
    }
    #undef PREFETCH

    // reduce across 16 column-lanes (xor<16 stays within quad group)
    #pragma unroll
    for (int mt = 0; mt < 2; ++mt)
        #pragma unroll
        for (int reg = 0; reg < 4; ++reg) {
            float p = lap[mt * 4 + reg], q = lan[mt * 4 + reg];
            #pragma unroll
            for (int o = 1; o < 16; o <<= 1) {
                p = fmaxf(p, __shfl_xor(p, o, 64));
                q = fminf(q, __shfl_xor(q, o, 64));
            }
            if (l == mt * 4 + reg) {   // one writer lane per quad
                int gi = rowbase + mt * 16 + quad * 4 + reg;
                float s = sq[gi];
                atomicMax(&ap[gi], __float_as_uint(fmaxf(s + p, 0.0f)));
                atomicMin(&an[gi], __float_as_uint(fmaxf(s + q, 0.0f)));
            }
        }

    // ---- fused final: last block to finish reduces the loss ----
    __threadfence();          // per-thread: atomics above visible device-wide
    __syncthreads();          // all threads of block past their fence; Bs free
    int* flag = (int*)&Bs[0][0];
    if (tid == 0) {
        unsigned old = __hip_atomic_fetch_add(done, 1u, __ATOMIC_ACQ_REL,
                                              __HIP_MEMORY_SCOPE_AGENT);
        *flag = (old == (unsigned)(64 * NSPLIT) - 1u) ? 1 : 0;
    }
    __syncthreads();
    if (*flag == 0) return;

    float v = 0.f;
    for (int i = tid; i < n; i += 256) {
        unsigned pb = __hip_atomic_load(&ap[i], __ATOMIC_RELAXED,
                                        __HIP_MEMORY_SCOPE_AGENT);
        unsigned qb = __hip_atomic_load(&an[i], __ATOMIC_RELAXED,
                                        __HIP_MEMORY_SCOPE_AGENT);
        v += fmaxf(__uint_as_float(pb) - __uint_as_float(qb) + MARGIN, 0.0f);
    }
    #pragma unroll
    for (int o = 32; o > 0; o >>= 1) v += __shfl_xor(v, o, 64);
    float* ws = (float*)&Bs[0][64];
    __syncthreads();
    if (lane == 0) ws[wid] = v;
    __syncthreads();
    if (tid == 0) *out = ws[0] + ws[1] + ws[2] + ws[3];
}

extern "C" void kernel_launch(void* const* d_in, const int* in_sizes, int n_in,
                              void* d_out, int out_size, void* d_ws, size_t ws_size,
                              hipStream_t stream) {
    const float* x   = (const float*)d_in[0];
    const int*   tgt = (const int*)d_in[1];
    float* out = (float*)d_out;
    const int n = in_sizes[1];              // 8192

    char* w = (char*)d_ws;
    float*          sq   = (float*)w;          w += (size_t)n * 4;
    unsigned*       ap   = (unsigned*)w;       w += (size_t)n * 4;
    unsigned*       an   = (unsigned*)w;       w += (size_t)n * 4;
    unsigned*       done = (unsigned*)w;       w += 256;          // pad-aligned
    __hip_bfloat16* xb   = (__hip_bfloat16*)w;

    prep_kernel<<<n / 4, 256, 0, stream>>>(x, sq, ap, an, xb, done, n);
    dim3 grid(n / 128, NSPLIT);
    gram_kernel<<<grid, 256, 0, stream>>>(xb, sq, tgt, ap, an, done, out, n);
}

// Round 9
// 166.536 us; speedup vs baseline: 2.0629x; 2.0629x over previous
//
#include <hip/hip_runtime.h>
#include <hip/hip_bf16.h>

#define D 128
#define MARGIN 0.5f
#define NSPLIT 16      // 64 x 16 = 1024 blocks = 4/CU

typedef __attribute__((ext_vector_type(8))) short bf16x8;
typedef __attribute__((ext_vector_type(4))) float f32x4;

// ---------------- prep: bf16 convert + sq + init ----------------
__global__ void prep_kernel(const float* __restrict__ x,
                            float* __restrict__ sq,
                            unsigned* __restrict__ ap,
                            unsigned* __restrict__ an,
                            __hip_bfloat16* __restrict__ xb,
                            unsigned* __restrict__ done, int n) {
    int tid = threadIdx.x;
    int row = blockIdx.x * 4 + (tid >> 6);
    int lane = tid & 63;
    const float2* xr = (const float2*)(x + (size_t)row * D);
    float2 v = xr[lane];
    __hip_bfloat162 b2;
    b2.x = __float2bfloat16(v.x);
    b2.y = __float2bfloat16(v.y);
    ((__hip_bfloat162*)(xb + (size_t)row * D))[lane] = b2;
    float s = v.x * v.x + v.y * v.y;
    #pragma unroll
    for (int o = 32; o > 0; o >>= 1) s += __shfl_xor(s, o, 64);
    if (lane == 0) {
        sq[row] = s;
        ap[row] = 0u;            // dist >= 0 -> 0 is a valid -inf for max
        an[row] = 0x7F800000u;   // +inf bits
    }
    if (blockIdx.x == 0 && tid == 0) *done = 0u;
}

// ---------------- gram: async B staging + fused final (last-block) -------
// R6 config exactly: __launch_bounds__(256,4) (VGPR cap 128 -- live state is
// ~90-100; R5/R8 proved any cap below that spills to scratch at 100+MB),
// 32KB LDS double-buffer, 4 blocks/CU. Staging via global_load_lds w=16
// (no VGPR round trip). XOR swizzle on global src addr; ds_read frags
// 2-way (free). Last finishing block reduces the loss (saves a ~6us launch).
__launch_bounds__(256, 4)
__global__ void gram_kernel(const __hip_bfloat16* __restrict__ xb,
                            const float* __restrict__ sq,
                            const int* __restrict__ tgt,
                            unsigned* __restrict__ ap,
                            unsigned* __restrict__ an,
                            unsigned* __restrict__ done,
                            float* __restrict__ out, int n) {
    __shared__ __align__(16) __hip_bfloat16 Bs[2][64 * D];

    const int tid  = threadIdx.x;
    const int wid  = tid >> 6;
    const int lane = tid & 63;
    const int quad = lane >> 4;
    const int l    = lane & 15;
    const int i0   = blockIdx.x * 128;
    const int jspan = n / NSPLIT;          // 512
    const int njit  = jspan / 64;          // 8
    const int j0    = blockIdx.y * jspan;
    const int rowbase = i0 + wid * 32;
    const unsigned nblocks = (unsigned)((n / 128) * NSPLIT);

    // A fragments, register-resident: lane holds A[m=l][k=quad*8+j]
    bf16x8 afrag[2][4];
    {
        const __hip_bfloat16* abase = xb + (size_t)(rowbase + l) * D + quad * 8;
        #pragma unroll
        for (int mt = 0; mt < 2; ++mt)
            #pragma unroll
            for (int ks = 0; ks < 4; ++ks)
                afrag[mt][ks] = *(const bf16x8*)(abase + (size_t)mt * 16 * D + ks * 32);
    }

    int li[2][4];
    #pragma unroll
    for (int mt = 0; mt < 2; ++mt)
        #pragma unroll
        for (int reg = 0; reg < 4; ++reg)
            li[mt][reg] = tgt[rowbase + mt * 16 + quad * 4 + reg];

    float lap[8], lan[8];
    #pragma unroll
    for (int k = 0; k < 8; ++k) { lap[k] = -1e30f; lan[k] = 1e30f; }

    const int q0 = wid * 256;
    const char* xbb = (const char*)xb;

    #define PREFETCH(jt0, buf)                                                \
        do {                                                                  \
            _Pragma("unroll")                                                 \
            for (int i_ = 0; i_ < 4; ++i_) {                                  \
                int q_ = q0 + i_ * 64 + lane;                                 \
                int r_ = q_ >> 4;                                             \
                int c_ = (q_ & 15) ^ (r_ & 15);                               \
                const char* g_ = xbb + (size_t)((jt0) + r_) * 256             \
                                     + (size_t)c_ * 16;                       \
                char* l_ = (char*)&Bs[buf][0] + (size_t)(q0 + i_ * 64) * 16;  \
                __builtin_amdgcn_global_load_lds(                             \
                    (const __attribute__((address_space(1))) void*)g_,        \
                    (__attribute__((address_space(3))) void*)l_, 16, 0, 0);   \
            }                                                                 \
        } while (0)

    PREFETCH(j0, 0);
    __syncthreads();

    for (int jj = 0; jj < njit; ++jj) {
        const int cur = jj & 1;
        if (jj < njit - 1) PREFETCH(j0 + (jj + 1) * 64, cur ^ 1);   // async

        const char* Bb = (const char*)&Bs[cur][0];
        const int jbase = j0 + jj * 64;
        #pragma unroll
        for (int jt = 0; jt < 4; ++jt) {
            f32x4 acc0 = (f32x4){0.f, 0.f, 0.f, 0.f};
            f32x4 acc1 = (f32x4){0.f, 0.f, 0.f, 0.f};
            #pragma unroll
            for (int ks = 0; ks < 4; ++ks) {
                int q = (jt * 16 + l) * 16 + ((ks * 4 + quad) ^ l);
                bf16x8 bfr = *(const bf16x8*)(Bb + (size_t)q * 16);
                acc0 = __builtin_amdgcn_mfma_f32_16x16x32_bf16(afrag[0][ks], bfr, acc0, 0, 0, 0);
                acc1 = __builtin_amdgcn_mfma_f32_16x16x32_bf16(afrag[1][ks], bfr, acc1, 0, 0, 0);
            }
            float sjc = sq[jbase + jt * 16 + l];
            int   tjc = tgt[jbase + jt * 16 + l];
            #pragma unroll
            for (int reg = 0; reg < 4; ++reg) {
                float t0 = fmaf(-2.0f, acc0[reg], sjc);
                float t1 = fmaf(-2.0f, acc1[reg], sjc);
                bool s0 = (li[0][reg] == tjc);
                bool s1 = (li[1][reg] == tjc);
                lap[reg]     = fmaxf(lap[reg],     s0 ? t0 : -1e30f);
                lan[reg]     = fminf(lan[reg],     s0 ? 1e30f : t0);
                lap[4 + reg] = fmaxf(lap[4 + reg], s1 ? t1 : -1e30f);
                lan[4 + reg] = fminf(lan[4 + reg], s1 ? 1e30f : t1);
            }
        }
        __syncthreads();
    }
    #undef PREFETCH

    // reduce across 16 column-lanes (xor<16 stays within quad group)
    #pragma unroll
    for (int mt = 0; mt < 2; ++mt)
        #pragma unroll
        for (int reg = 0; reg < 4; ++reg) {
            float p = lap[mt * 4 + reg], q = lan[mt * 4 + reg];
            #pragma unroll
            for (int o = 1; o < 16; o <<= 1) {
                p = fmaxf(p, __shfl_xor(p, o, 64));
                q = fminf(q, __shfl_xor(q, o, 64));
            }
            if (l == mt * 4 + reg) {   // one writer lane per quad
                int gi = rowbase + mt * 16 + quad * 4 + reg;
                float s = sq[gi];
                atomicMax(&ap[gi], __float_as_uint(fmaxf(s + p, 0.0f)));
                atomicMin(&an[gi], __float_as_uint(fmaxf(s + q, 0.0f)));
            }
        }

    // ---- fused final: last block to finish reduces the loss ----
    __threadfence();          // atomics above visible device-wide
    __syncthreads();          // whole block past its fence; Bs reusable
    int* flag = (int*)&Bs[0][0];
    if (tid == 0) {
        unsigned old = __hip_atomic_fetch_add(done, 1u, __ATOMIC_ACQ_REL,
                                              __HIP_MEMORY_SCOPE_AGENT);
        *flag = (old == nblocks - 1u) ? 1 : 0;
    }
    __syncthreads();
    if (*flag == 0) return;

    float v = 0.f;
    for (int i = tid; i < n; i += 256) {
        unsigned pb = __hip_atomic_load(&ap[i], __ATOMIC_RELAXED,
                                        __HIP_MEMORY_SCOPE_AGENT);
        unsigned qb = __hip_atomic_load(&an[i], __ATOMIC_RELAXED,
                                        __HIP_MEMORY_SCOPE_AGENT);
        v += fmaxf(__uint_as_float(pb) - __uint_as_float(qb) + MARGIN, 0.0f);
    }
    #pragma unroll
    for (int o = 32; o > 0; o >>= 1) v += __shfl_xor(v, o, 64);
    float* ws = (float*)&Bs[0][64];
    __syncthreads();
    if (lane == 0) ws[wid] = v;
    __syncthreads();
    if (tid == 0) *out = ws[0] + ws[1] + ws[2] + ws[3];
}

extern "C" void kernel_launch(void* const* d_in, const int* in_sizes, int n_in,
                              void* d_out, int out_size, void* d_ws, size_t ws_size,
                              hipStream_t stream) {
    const float* x   = (const float*)d_in[0];
    const int*   tgt = (const int*)d_in[1];
    float* out = (float*)d_out;
    const int n = in_sizes[1];              // 8192

    char* w = (char*)d_ws;
    float*          sq   = (float*)w;          w += (size_t)n * 4;
    unsigned*       ap   = (unsigned*)w;       w += (size_t)n * 4;
    unsigned*       an   = (unsigned*)w;       w += (size_t)n * 4;
    unsigned*       done = (unsigned*)w;       w += 256;
    __hip_bfloat16* xb   = (__hip_bfloat16*)w;

    prep_kernel<<<n / 4, 256, 0, stream>>>(x, sq, ap, an, xb, done, n);
    dim3 grid(n / 128, NSPLIT);
    gram_kernel<<<grid, 256, 0, stream>>>(xb, sq, tgt, ap, an, done, out, n);
}

// Round 10
// 99.180 us; speedup vs baseline: 3.4638x; 1.6791x over previous
//
#include <hip/hip_runtime.h>
#include <hip/hip_bf16.h>

#define D 128
#define MARGIN 0.5f
#define NSPLIT 16      // 64 x 16 = 1024 blocks = 4/CU

typedef __attribute__((ext_vector_type(8))) short bf16x8;
typedef __attribute__((ext_vector_type(4))) float f32x4;

// ---------------- prep: bf16 convert + sq + init ----------------
__global__ void prep_kernel(const float* __restrict__ x,
                            float* __restrict__ sq,
                            unsigned* __restrict__ ap,
                            unsigned* __restrict__ an,
                            __hip_bfloat16* __restrict__ xb,
                            unsigned* __restrict__ done, int n) {
    int tid = threadIdx.x;
    int row = blockIdx.x * 4 + (tid >> 6);
    int lane = tid & 63;
    const float2* xr = (const float2*)(x + (size_t)row * D);
    float2 v = xr[lane];
    __hip_bfloat162 b2;
    b2.x = __float2bfloat16(v.x);
    b2.y = __float2bfloat16(v.y);
    ((__hip_bfloat162*)(xb + (size_t)row * D))[lane] = b2;
    float s = v.x * v.x + v.y * v.y;
    #pragma unroll
    for (int o = 32; o > 0; o >>= 1) s += __shfl_xor(s, o, 64);
    if (lane == 0) {
        sq[row] = s;
        ap[row] = 0u;            // dist >= 0 -> 0 is a valid -inf for max
        an[row] = 0x7F800000u;   // +inf bits
    }
    if (blockIdx.x == 0 && tid == 0) *done = 0u;
}

// ---------------- gram: async B staging + fused final (cheap sync) -------
// R6 K-loop exactly. Fused last-block final WITHOUT per-block L2
// writeback/invalidate (R9's +80us): ap/an atomicMax/Min are device-scope
// -> performed at the coherent point (bypass incoherent per-XCD L2s), so
// visibility needs only COMPLETION ordering, which __syncthreads already
// gives (compiler emits s_waitcnt vmcnt(0) before s_barrier). done counter
// is a relaxed agent-scope RMW; reader uses relaxed agent atomic loads.
__launch_bounds__(256, 4)
__global__ void gram_kernel(const __hip_bfloat16* __restrict__ xb,
                            const float* __restrict__ sq,
                            const int* __restrict__ tgt,
                            unsigned* __restrict__ ap,
                            unsigned* __restrict__ an,
                            unsigned* __restrict__ done,
                            float* __restrict__ out, int n) {
    __shared__ __align__(16) __hip_bfloat16 Bs[2][64 * D];

    const int tid  = threadIdx.x;
    const int wid  = tid >> 6;
    const int lane = tid & 63;
    const int quad = lane >> 4;
    const int l    = lane & 15;
    const int i0   = blockIdx.x * 128;
    const int jspan = n / NSPLIT;          // 512
    const int njit  = jspan / 64;          // 8
    const int j0    = blockIdx.y * jspan;
    const int rowbase = i0 + wid * 32;
    const unsigned nblocks = (unsigned)((n / 128) * NSPLIT);

    // A fragments, register-resident: lane holds A[m=l][k=quad*8+j]
    bf16x8 afrag[2][4];
    {
        const __hip_bfloat16* abase = xb + (size_t)(rowbase + l) * D + quad * 8;
        #pragma unroll
        for (int mt = 0; mt < 2; ++mt)
            #pragma unroll
            for (int ks = 0; ks < 4; ++ks)
                afrag[mt][ks] = *(const bf16x8*)(abase + (size_t)mt * 16 * D + ks * 32);
    }

    int li[2][4];
    #pragma unroll
    for (int mt = 0; mt < 2; ++mt)
        #pragma unroll
        for (int reg = 0; reg < 4; ++reg)
            li[mt][reg] = tgt[rowbase + mt * 16 + quad * 4 + reg];

    float lap[8], lan[8];
    #pragma unroll
    for (int k = 0; k < 8; ++k) { lap[k] = -1e30f; lan[k] = 1e30f; }

    const int q0 = wid * 256;
    const char* xbb = (const char*)xb;

    #define PREFETCH(jt0, buf)                                                \
        do {                                                                  \
            _Pragma("unroll")                                                 \
            for (int i_ = 0; i_ < 4; ++i_) {                                  \
                int q_ = q0 + i_ * 64 + lane;                                 \
                int r_ = q_ >> 4;                                             \
                int c_ = (q_ & 15) ^ (r_ & 15);                               \
                const char* g_ = xbb + (size_t)((jt0) + r_) * 256             \
                                     + (size_t)c_ * 16;                       \
                char* l_ = (char*)&Bs[buf][0] + (size_t)(q0 + i_ * 64) * 16;  \
                __builtin_amdgcn_global_load_lds(                             \
                    (const __attribute__((address_space(1))) void*)g_,        \
                    (__attribute__((address_space(3))) void*)l_, 16, 0, 0);   \
            }                                                                 \
        } while (0)

    PREFETCH(j0, 0);
    __syncthreads();

    for (int jj = 0; jj < njit; ++jj) {
        const int cur = jj & 1;
        if (jj < njit - 1) PREFETCH(j0 + (jj + 1) * 64, cur ^ 1);   // async

        const char* Bb = (const char*)&Bs[cur][0];
        const int jbase = j0 + jj * 64;
        #pragma unroll
        for (int jt = 0; jt < 4; ++jt) {
            f32x4 acc0 = (f32x4){0.f, 0.f, 0.f, 0.f};
            f32x4 acc1 = (f32x4){0.f, 0.f, 0.f, 0.f};
            #pragma unroll
            for (int ks = 0; ks < 4; ++ks) {
                int q = (jt * 16 + l) * 16 + ((ks * 4 + quad) ^ l);
                bf16x8 bfr = *(const bf16x8*)(Bb + (size_t)q * 16);
                acc0 = __builtin_amdgcn_mfma_f32_16x16x32_bf16(afrag[0][ks], bfr, acc0, 0, 0, 0);
                acc1 = __builtin_amdgcn_mfma_f32_16x16x32_bf16(afrag[1][ks], bfr, acc1, 0, 0, 0);
            }
            float sjc = sq[jbase + jt * 16 + l];
            int   tjc = tgt[jbase + jt * 16 + l];
            #pragma unroll
            for (int reg = 0; reg < 4; ++reg) {
                float t0 = fmaf(-2.0f, acc0[reg], sjc);
                float t1 = fmaf(-2.0f, acc1[reg], sjc);
                bool s0 = (li[0][reg] == tjc);
                bool s1 = (li[1][reg] == tjc);
                lap[reg]     = fmaxf(lap[reg],     s0 ? t0 : -1e30f);
                lan[reg]     = fminf(lan[reg],     s0 ? 1e30f : t0);
                lap[4 + reg] = fmaxf(lap[4 + reg], s1 ? t1 : -1e30f);
                lan[4 + reg] = fminf(lan[4 + reg], s1 ? 1e30f : t1);
            }
        }
        __syncthreads();
    }
    #undef PREFETCH

    // reduce across 16 column-lanes (xor<16 stays within quad group)
    #pragma unroll
    for (int mt = 0; mt < 2; ++mt)
        #pragma unroll
        for (int reg = 0; reg < 4; ++reg) {
            float p = lap[mt * 4 + reg], q = lan[mt * 4 + reg];
            #pragma unroll
            for (int o = 1; o < 16; o <<= 1) {
                p = fmaxf(p, __shfl_xor(p, o, 64));
                q = fminf(q, __shfl_xor(q, o, 64));
            }
            if (l == mt * 4 + reg) {   // one writer lane per quad
                int gi = rowbase + mt * 16 + quad * 4 + reg;
                float s = sq[gi];
                atomicMax(&ap[gi], __float_as_uint(fmaxf(s + p, 0.0f)));
                atomicMin(&an[gi], __float_as_uint(fmaxf(s + q, 0.0f)));
            }
        }

    // ---- fused final: cheap completion ordering, no cache maintenance ----
    // __syncthreads drains each wave's vmem (incl. the atomics above) before
    // any thread passes -> all block atomics complete at the coherent point.
    __syncthreads();
    int* flag = (int*)&Bs[0][0];
    if (tid == 0) {
        unsigned old = __hip_atomic_fetch_add(done, 1u, __ATOMIC_RELAXED,
                                              __HIP_MEMORY_SCOPE_AGENT);
        *flag = (old == nblocks - 1u) ? 1 : 0;
    }
    __syncthreads();
    if (*flag == 0) return;

    float v = 0.f;
    for (int i = tid; i < n; i += 256) {
        unsigned pb = __hip_atomic_load(&ap[i], __ATOMIC_RELAXED,
                                        __HIP_MEMORY_SCOPE_AGENT);
        unsigned qb = __hip_atomic_load(&an[i], __ATOMIC_RELAXED,
                                        __HIP_MEMORY_SCOPE_AGENT);
        v += fmaxf(__uint_as_float(pb) - __uint_as_float(qb) + MARGIN, 0.0f);
    }
    #pragma unroll
    for (int o = 32; o > 0; o >>= 1) v += __shfl_xor(v, o, 64);
    float* ws = (float*)&Bs[0][64];
    __syncthreads();
    if (lane == 0) ws[wid] = v;
    __syncthreads();
    if (tid == 0) *out = ws[0] + ws[1] + ws[2] + ws[3];
}

extern "C" void kernel_launch(void* const* d_in, const int* in_sizes, int n_in,
                              void* d_out, int out_size, void* d_ws, size_t ws_size,
                              hipStream_t stream) {
    const float* x   = (const float*)d_in[0];
    const int*   tgt = (const int*)d_in[1];
    float* out = (float*)d_out;
    const int n = in_sizes[1];              // 8192

    char* w = (char*)d_ws;
    float*          sq   = (float*)w;          w += (size_t)n * 4;
    unsigned*       ap   = (unsigned*)w;       w += (size_t)n * 4;
    unsigned*       an   = (unsigned*)w;       w += (size_t)n * 4;
    unsigned*       done = (unsigned*)w;       w += 256;
    __hip_bfloat16* xb   = (__hip_bfloat16*)w;

    prep_kernel<<<n / 4, 256, 0, stream>>>(x, sq, ap, an, xb, done, n);
    dim3 grid(n / 128, NSPLIT);
    gram_kernel<<<grid, 256, 0, stream>>>(xb, sq, tgt, ap, an, done, out, n);
}

// Round 11
// 90.632 us; speedup vs baseline: 3.7905x; 1.0943x over previous
//
#include <hip/hip_runtime.h>
#include <hip/hip_bf16.h>

#define D 128
#define MARGIN 0.5f
#define NSPLIT 16      // 64 x 16 = 1024 blocks = 4/CU

typedef __attribute__((ext_vector_type(8))) short bf16x8;
typedef __attribute__((ext_vector_type(4))) float f32x4;

// ---------------- prep: bf16 convert + sq + init ----------------
__global__ void prep_kernel(const float* __restrict__ x,
                            float* __restrict__ sq,
                            unsigned* __restrict__ ap,
                            unsigned* __restrict__ an,
                            __hip_bfloat16* __restrict__ xb,
                            unsigned* __restrict__ done, int n) {
    int tid = threadIdx.x;
    int row = blockIdx.x * 4 + (tid >> 6);
    int lane = tid & 63;
    const float2* xr = (const float2*)(x + (size_t)row * D);
    float2 v = xr[lane];
    __hip_bfloat162 b2;
    b2.x = __float2bfloat16(v.x);
    b2.y = __float2bfloat16(v.y);
    ((__hip_bfloat162*)(xb + (size_t)row * D))[lane] = b2;
    float s = v.x * v.x + v.y * v.y;
    #pragma unroll
    for (int o = 32; o > 0; o >>= 1) s += __shfl_xor(s, o, 64);
    if (lane == 0) {
        sq[row] = s;
        ap[row] = 0u;            // dist >= 0 -> 0 is a valid -inf for max
        an[row] = 0x7F800000u;   // +inf bits
    }
    if (blockIdx.x == 0 && tid == 0) *done = 0u;
}

// ---------------- gram: async B staging + fused final (fast tail) --------
// R10 K-loop. Changes: (1) j-window sq/tgt staged to LDS once (in-loop
// global loads -> ds_read_b32); (2) last-block reduction uses ONE agent
// acquire fence (single L1/L2 inv in an already-finished block — not R9's
// per-block storm) + plain vectorized uint4 loads instead of 64 serial
// coherent-point atomic loads (that was R10's ~7us single-block tail).
__launch_bounds__(256, 4)
__global__ void gram_kernel(const __hip_bfloat16* __restrict__ xb,
                            const float* __restrict__ sq,
                            const int* __restrict__ tgt,
                            unsigned* __restrict__ ap,
                            unsigned* __restrict__ an,
                            unsigned* __restrict__ done,
                            float* __restrict__ out, int n) {
    __shared__ __align__(16) __hip_bfloat16 Bs[2][64 * D];
    __shared__ float sqw[512];
    __shared__ int   tgw[512];

    const int tid  = threadIdx.x;
    const int wid  = tid >> 6;
    const int lane = tid & 63;
    const int quad = lane >> 4;
    const int l    = lane & 15;
    const int i0   = blockIdx.x * 128;
    const int jspan = n / NSPLIT;          // 512
    const int njit  = jspan / 64;          // 8
    const int j0    = blockIdx.y * jspan;
    const int rowbase = i0 + wid * 32;
    const unsigned nblocks = (unsigned)((n / 128) * NSPLIT);

    // A fragments, register-resident: lane holds A[m=l][k=quad*8+j]
    bf16x8 afrag[2][4];
    {
        const __hip_bfloat16* abase = xb + (size_t)(rowbase + l) * D + quad * 8;
        #pragma unroll
        for (int mt = 0; mt < 2; ++mt)
            #pragma unroll
            for (int ks = 0; ks < 4; ++ks)
                afrag[mt][ks] = *(const bf16x8*)(abase + (size_t)mt * 16 * D + ks * 32);
    }

    int li[2][4];
    #pragma unroll
    for (int mt = 0; mt < 2; ++mt)
        #pragma unroll
        for (int reg = 0; reg < 4; ++reg)
            li[mt][reg] = tgt[rowbase + mt * 16 + quad * 4 + reg];

    float lap[8], lan[8];
    #pragma unroll
    for (int k = 0; k < 8; ++k) { lap[k] = -1e30f; lan[k] = 1e30f; }

    const int q0 = wid * 256;
    const char* xbb = (const char*)xb;

    #define PREFETCH(jt0, buf)                                                \
        do {                                                                  \
            _Pragma("unroll")                                                 \
            for (int i_ = 0; i_ < 4; ++i_) {                                  \
                int q_ = q0 + i_ * 64 + lane;                                 \
                int r_ = q_ >> 4;                                             \
                int c_ = (q_ & 15) ^ (r_ & 15);                               \
                const char* g_ = xbb + (size_t)((jt0) + r_) * 256             \
                                     + (size_t)c_ * 16;                       \
                char* l_ = (char*)&Bs[buf][0] + (size_t)(q0 + i_ * 64) * 16;  \
                __builtin_amdgcn_global_load_lds(                             \
                    (const __attribute__((address_space(1))) void*)g_,        \
                    (__attribute__((address_space(3))) void*)l_, 16, 0, 0);   \
            }                                                                 \
        } while (0)

    PREFETCH(j0, 0);
    // stage j-window sq/tgt (512 each) into LDS, 2 elems/thread
    {
        int a = tid, b = tid + 256;
        sqw[a] = sq[j0 + a];  sqw[b] = sq[j0 + b];
        tgw[a] = tgt[j0 + a]; tgw[b] = tgt[j0 + b];
    }
    __syncthreads();

    for (int jj = 0; jj < njit; ++jj) {
        const int cur = jj & 1;
        if (jj < njit - 1) PREFETCH(j0 + (jj + 1) * 64, cur ^ 1);   // async

        const char* Bb = (const char*)&Bs[cur][0];
        const int jloc = jj * 64;
        #pragma unroll
        for (int jt = 0; jt < 4; ++jt) {
            f32x4 acc0 = (f32x4){0.f, 0.f, 0.f, 0.f};
            f32x4 acc1 = (f32x4){0.f, 0.f, 0.f, 0.f};
            #pragma unroll
            for (int ks = 0; ks < 4; ++ks) {
                int q = (jt * 16 + l) * 16 + ((ks * 4 + quad) ^ l);
                bf16x8 bfr = *(const bf16x8*)(Bb + (size_t)q * 16);
                acc0 = __builtin_amdgcn_mfma_f32_16x16x32_bf16(afrag[0][ks], bfr, acc0, 0, 0, 0);
                acc1 = __builtin_amdgcn_mfma_f32_16x16x32_bf16(afrag[1][ks], bfr, acc1, 0, 0, 0);
            }
            float sjc = sqw[jloc + jt * 16 + l];
            int   tjc = tgw[jloc + jt * 16 + l];
            #pragma unroll
            for (int reg = 0; reg < 4; ++reg) {
                float t0 = fmaf(-2.0f, acc0[reg], sjc);
                float t1 = fmaf(-2.0f, acc1[reg], sjc);
                bool s0 = (li[0][reg] == tjc);
                bool s1 = (li[1][reg] == tjc);
                lap[reg]     = fmaxf(lap[reg],     s0 ? t0 : -1e30f);
                lan[reg]     = fminf(lan[reg],     s0 ? 1e30f : t0);
                lap[4 + reg] = fmaxf(lap[4 + reg], s1 ? t1 : -1e30f);
                lan[4 + reg] = fminf(lan[4 + reg], s1 ? 1e30f : t1);
            }
        }
        __syncthreads();
    }
    #undef PREFETCH

    // reduce across 16 column-lanes (xor<16 stays within quad group)
    #pragma unroll
    for (int mt = 0; mt < 2; ++mt)
        #pragma unroll
        for (int reg = 0; reg < 4; ++reg) {
            float p = lap[mt * 4 + reg], q = lan[mt * 4 + reg];
            #pragma unroll
            for (int o = 1; o < 16; o <<= 1) {
                p = fmaxf(p, __shfl_xor(p, o, 64));
                q = fminf(q, __shfl_xor(q, o, 64));
            }
            if (l == mt * 4 + reg) {   // one writer lane per quad
                int gi = rowbase + mt * 16 + quad * 4 + reg;
                float s = sq[gi];
                atomicMax(&ap[gi], __float_as_uint(fmaxf(s + p, 0.0f)));
                atomicMin(&an[gi], __float_as_uint(fmaxf(s + q, 0.0f)));
            }
        }

    // ---- fused final: last block reduces; acquire fence + vector loads ---
    // __syncthreads drains vmcnt -> this block's atomics complete before the
    // done increment can be observed.
    __syncthreads();
    int* flag = (int*)&Bs[0][0];
    if (tid == 0) {
        unsigned old = __hip_atomic_fetch_add(done, 1u, __ATOMIC_RELAXED,
                                              __HIP_MEMORY_SCOPE_AGENT);
        *flag = (old == nblocks - 1u) ? 1 : 0;
    }
    __syncthreads();
    if (*flag == 0) return;

    // single acquire fence: invalidate stale L1/L2 so plain loads observe
    // the coherent-point values written by all blocks' atomics.
    __builtin_amdgcn_fence(__ATOMIC_ACQUIRE, "agent");

    float v = 0.f;
    const uint4* ap4 = (const uint4*)ap;
    const uint4* an4 = (const uint4*)an;
    for (int b = tid; b < n / 4; b += 256) {   // 8 iters, independent 16B loads
        uint4 pb = ap4[b];
        uint4 qb = an4[b];
        v += fmaxf(__uint_as_float(pb.x) - __uint_as_float(qb.x) + MARGIN, 0.0f);
        v += fmaxf(__uint_as_float(pb.y) - __uint_as_float(qb.y) + MARGIN, 0.0f);
        v += fmaxf(__uint_as_float(pb.z) - __uint_as_float(qb.z) + MARGIN, 0.0f);
        v += fmaxf(__uint_as_float(pb.w) - __uint_as_float(qb.w) + MARGIN, 0.0f);
    }
    #pragma unroll
    for (int o = 32; o > 0; o >>= 1) v += __shfl_xor(v, o, 64);
    float* ws = (float*)&Bs[0][64];
    __syncthreads();
    if (lane == 0) ws[wid] = v;
    __syncthreads();
    if (tid == 0) *out = ws[0] + ws[1] + ws[2] + ws[3];
}

extern "C" void kernel_launch(void* const* d_in, const int* in_sizes, int n_in,
                              void* d_out, int out_size, void* d_ws, size_t ws_size,
                              hipStream_t stream) {
    const float* x   = (const float*)d_in[0];
    const int*   tgt = (const int*)d_in[1];
    float* out = (float*)d_out;
    const int n = in_sizes[1];              // 8192

    char* w = (char*)d_ws;
    float*          sq   = (float*)w;          w += (size_t)n * 4;
    unsigned*       ap   = (unsigned*)w;       w += (size_t)n * 4;
    unsigned*       an   = (unsigned*)w;       w += (size_t)n * 4;
    unsigned*       done = (unsigned*)w;       w += 256;
    __hip_bfloat16* xb   = (__hip_bfloat16*)w;

    prep_kernel<<<n / 4, 256, 0, stream>>>(x, sq, ap, an, xb, done, n);
    dim3 grid(n / 128, NSPLIT);
    gram_kernel<<<grid, 256, 0, stream>>>(xb, sq, tgt, ap, an, done, out, n);
}